// Round 1
// baseline (882.469 us; speedup 1.0000x reference)
//
#include <hip/hip_runtime.h>

#define NN 100000
#define NE 1600000

typedef __attribute__((ext_vector_type(8))) short short8;
typedef __attribute__((ext_vector_type(4))) float f32x4;

// RNE float -> bf16 bits
__device__ __forceinline__ short f2b(float x) {
    unsigned u = __builtin_bit_cast(unsigned, x);
    u = (u + 0x7FFFu + ((u >> 16) & 1u)) >> 16;
    return (short)u;
}

__device__ __forceinline__ float selu_f(float x) {
    const float scale = 1.0507009873554805f;
    const float asc   = 1.7580993408473766f;  // alpha * scale
    return x > 0.f ? scale * x : asc * (__expf(x) - 1.f);
}

__device__ __forceinline__ short8 pack8(const float* __restrict__ p) {
    const float4 a = *reinterpret_cast<const float4*>(p);
    const float4 b = *reinterpret_cast<const float4*>(p + 4);
    short8 r;
    r[0] = f2b(a.x); r[1] = f2b(a.y); r[2] = f2b(a.z); r[3] = f2b(a.w);
    r[4] = f2b(b.x); r[5] = f2b(b.y); r[6] = f2b(b.z); r[7] = f2b(b.w);
    return r;
}

__device__ __forceinline__ short8 pack8s(const float* __restrict__ p, float s) {
    const float4 a = *reinterpret_cast<const float4*>(p);
    const float4 b = *reinterpret_cast<const float4*>(p + 4);
    short8 r;
    r[0] = f2b(a.x * s); r[1] = f2b(a.y * s); r[2] = f2b(a.z * s); r[3] = f2b(a.w * s);
    r[4] = f2b(b.x * s); r[5] = f2b(b.y * s); r[6] = f2b(b.z * s); r[7] = f2b(b.w * s);
    return r;
}

// B-fragment for 16x16x32: lane holds W[t*32 + q*8 + j][n*16 + p], j=0..7
__device__ __forceinline__ short8 wfrag(const float* __restrict__ W, int t, int n, int p, int q) {
    const float* base = W + (t * 32 + q * 8) * 64 + n * 16 + p;
    short8 r;
#pragma unroll
    for (int j = 0; j < 8; ++j) r[j] = f2b(base[j * 64]);
    return r;
}

__device__ __forceinline__ f32x4 mm(short8 a, short8 b, f32x4 c) {
    return __builtin_amdgcn_mfma_f32_16x16x32_bf16(a, b, c, 0, 0, 0);
}

// ---------------- Edge MLP + scatter-add ----------------
__global__ __launch_bounds__(256) void edge_kernel(
    const float* __restrict__ x, const int* __restrict__ row, const int* __restrict__ col,
    const float* __restrict__ ea,
    const float* __restrict__ W1a, const float* __restrict__ b1a,
    const float* __restrict__ W1b, const float* __restrict__ b1b,
    float* __restrict__ summed, float* __restrict__ counts)
{
    __shared__ __attribute__((aligned(16))) short hlds[4][16 * 72];
    const int lane = threadIdx.x & 63;
    const int wid  = threadIdx.x >> 6;
    const int p = lane & 15, q = lane >> 4;
    short* hl = hlds[wid];

    short8 B1[4][4], B2[2][4];
#pragma unroll
    for (int t = 0; t < 4; ++t)
#pragma unroll
        for (int n = 0; n < 4; ++n) B1[t][n] = wfrag(W1a, t, n, p, q);
#pragma unroll
    for (int t = 0; t < 2; ++t)
#pragma unroll
        for (int n = 0; n < 4; ++n) B2[t][n] = wfrag(W1b, t, n, p, q);
    float bias1[4], bias2[4];
#pragma unroll
    for (int n = 0; n < 4; ++n) { bias1[n] = b1a[n * 16 + p]; bias2[n] = b1b[n * 16 + p]; }

    const int nwave = gridDim.x * 4;
    for (int tile = blockIdx.x * 4 + wid; tile < NE / 16; tile += nwave) {
        const int e  = tile * 16 + p;
        const int rs = row[e];
        const float* xr = x + rs * 64 + q * 8;
        const float* er = ea + e * 64 + q * 8;
        short8 a0 = pack8(xr);
        short8 a1 = pack8(xr + 32);
        short8 a2 = pack8(er);
        short8 a3 = pack8(er + 32);

        f32x4 acc[4];
#pragma unroll
        for (int n = 0; n < 4; ++n) acc[n] = (f32x4){0.f, 0.f, 0.f, 0.f};
#pragma unroll
        for (int n = 0; n < 4; ++n) {
            acc[n] = mm(a0, B1[0][n], acc[n]);
            acc[n] = mm(a1, B1[1][n], acc[n]);
            acc[n] = mm(a2, B1[2][n], acc[n]);
            acc[n] = mm(a3, B1[3][n], acc[n]);
        }
        // selu + bias; D layout: row=(q*4+i) edge, col=(n*16+p) feature -> LDS transpose
#pragma unroll
        for (int n = 0; n < 4; ++n)
#pragma unroll
            for (int i = 0; i < 4; ++i)
                hl[(q * 4 + i) * 72 + n * 16 + p] = f2b(selu_f(acc[n][i] + bias1[n]));

        // A-frags of H: lane reads row p, k = t*32 + q*8 .. +8 (same-wave LDS, in-order)
        short8 h0 = *reinterpret_cast<const short8*>(hl + p * 72 + q * 8);
        short8 h1 = *reinterpret_cast<const short8*>(hl + p * 72 + 32 + q * 8);

        f32x4 acc2[4];
#pragma unroll
        for (int n = 0; n < 4; ++n) acc2[n] = (f32x4){0.f, 0.f, 0.f, 0.f};
#pragma unroll
        for (int n = 0; n < 4; ++n) {
            acc2[n] = mm(h0, B2[0][n], acc2[n]);
            acc2[n] = mm(h1, B2[1][n], acc2[n]);
        }

        int cd[4];
#pragma unroll
        for (int i = 0; i < 4; ++i) cd[i] = col[tile * 16 + q * 4 + i];
#pragma unroll
        for (int n = 0; n < 4; ++n)
#pragma unroll
            for (int i = 0; i < 4; ++i)
                unsafeAtomicAdd(&summed[cd[i] * 64 + n * 16 + p], acc2[n][i] + bias2[n]);
        if (lane < 16) unsafeAtomicAdd(&counts[col[e]], 1.0f);
    }
}

// ---------------- Node MLP ----------------
__global__ __launch_bounds__(256) void node_kernel(
    const float* __restrict__ x, const float* __restrict__ u, const int* __restrict__ batch,
    const float* __restrict__ summed, const float* __restrict__ counts,
    const float* __restrict__ W2a, const float* __restrict__ b2a,
    const float* __restrict__ W2b, const float* __restrict__ b2b,
    float* __restrict__ out)
{
    __shared__ __attribute__((aligned(16))) short hlds[4][16 * 72];
    const int lane = threadIdx.x & 63;
    const int wid  = threadIdx.x >> 6;
    const int p = lane & 15, q = lane >> 4;
    short* hl = hlds[wid];

    short8 BA[6][4], BB[2][4];
#pragma unroll
    for (int t = 0; t < 6; ++t)
#pragma unroll
        for (int n = 0; n < 4; ++n) BA[t][n] = wfrag(W2a, t, n, p, q);
#pragma unroll
    for (int t = 0; t < 2; ++t)
#pragma unroll
        for (int n = 0; n < 4; ++n) BB[t][n] = wfrag(W2b, t, n, p, q);
    float bias1[4], bias2[4];
#pragma unroll
    for (int n = 0; n < 4; ++n) { bias1[n] = b2a[n * 16 + p]; bias2[n] = b2b[n * 16 + p]; }

    const int nwave = gridDim.x * 4;
    for (int tile = blockIdx.x * 4 + wid; tile < NN / 16; tile += nwave) {
        const int v = tile * 16 + p;
        const float* xr = x + v * 64 + q * 8;
        short8 a0 = pack8(xr);
        short8 a1 = pack8(xr + 32);
        const float rc = 1.f / fmaxf(counts[v], 1.f);
        const float* sr = summed + v * 64 + q * 8;
        short8 a2 = pack8s(sr, rc);
        short8 a3 = pack8s(sr + 32, rc);
        const int g = batch[v];
        const float* ur = u + g * 64 + q * 8;
        short8 a4 = pack8(ur);
        short8 a5 = pack8(ur + 32);

        f32x4 acc[4];
#pragma unroll
        for (int n = 0; n < 4; ++n) acc[n] = (f32x4){0.f, 0.f, 0.f, 0.f};
#pragma unroll
        for (int n = 0; n < 4; ++n) {
            acc[n] = mm(a0, BA[0][n], acc[n]);
            acc[n] = mm(a1, BA[1][n], acc[n]);
            acc[n] = mm(a2, BA[2][n], acc[n]);
            acc[n] = mm(a3, BA[3][n], acc[n]);
            acc[n] = mm(a4, BA[4][n], acc[n]);
            acc[n] = mm(a5, BA[5][n], acc[n]);
        }
#pragma unroll
        for (int n = 0; n < 4; ++n)
#pragma unroll
            for (int i = 0; i < 4; ++i)
                hl[(q * 4 + i) * 72 + n * 16 + p] = f2b(selu_f(acc[n][i] + bias1[n]));

        short8 h0 = *reinterpret_cast<const short8*>(hl + p * 72 + q * 8);
        short8 h1 = *reinterpret_cast<const short8*>(hl + p * 72 + 32 + q * 8);

        f32x4 acc2[4];
#pragma unroll
        for (int n = 0; n < 4; ++n) acc2[n] = (f32x4){0.f, 0.f, 0.f, 0.f};
#pragma unroll
        for (int n = 0; n < 4; ++n) {
            acc2[n] = mm(h0, BB[0][n], acc2[n]);
            acc2[n] = mm(h1, BB[1][n], acc2[n]);
        }
#pragma unroll
        for (int n = 0; n < 4; ++n)
#pragma unroll
            for (int i = 0; i < 4; ++i)
                out[(tile * 16 + q * 4 + i) * 64 + n * 16 + p] = acc2[n][i] + bias2[n];
    }
}

extern "C" void kernel_launch(void* const* d_in, const int* in_sizes, int n_in,
                              void* d_out, int out_size, void* d_ws, size_t ws_size,
                              hipStream_t stream) {
    const float* x     = (const float*)d_in[0];
    const int*   ei    = (const int*)d_in[1];
    const float* ea    = (const float*)d_in[2];
    const float* u     = (const float*)d_in[3];
    const int*   batch = (const int*)d_in[4];
    const float* W1a   = (const float*)d_in[5];
    const float* b1a   = (const float*)d_in[6];
    const float* W1b   = (const float*)d_in[7];
    const float* b1b   = (const float*)d_in[8];
    const float* W2a   = (const float*)d_in[9];
    const float* b2a   = (const float*)d_in[10];
    const float* W2b   = (const float*)d_in[11];
    const float* b2b   = (const float*)d_in[12];
    float* out = (float*)d_out;

    float* summed = (float*)d_ws;                 // [NN][64]
    float* counts = summed + (size_t)NN * 64;     // [NN]

    hipMemsetAsync(d_ws, 0, ((size_t)NN * 64 + NN) * sizeof(float), stream);

    const int* row = ei;
    const int* col = ei + NE;
    edge_kernel<<<1024, 256, 0, stream>>>(x, row, col, ea, W1a, b1a, W1b, b1b, summed, counts);
    node_kernel<<<512, 256, 0, stream>>>(x, u, batch, summed, counts, W2a, b2a, W2b, b2b, out);
}